// Round 4
// baseline (122.258 us; speedup 1.0000x reference)
//
#include <hip/hip_runtime.h>

// CenterLoss: mean over B rows of clip(||x_b - centers[label_b]||^2, 1e-12, 1e12)
// labels are exact one-hot fp32 rows -> dense dot == row gather (bit-exact).
//
// R1: 8192 same-address atomics serialized (110 us). R2: per-block partials
// (total 116 us; main kernel ~22-26 us vs ~11 us HBM floor; ~85 us is fixed
// harness reset inside the timed window).
// R3/R4: one WAVE per row (4 rows / 256-block). No LDS, no barriers; one-hot
// index via shuffle-max; 20 VMEM loads in flight before the first dependent
// wait. R4 fix: __builtin_nontemporal_load needs a NATIVE vector type, not
// HIP's float4 struct -> use ext_vector_type(4).

#define BATCH 8192
#define NUM_CLASSES 751
#define FEAT_DIM 2048

typedef float fvec4 __attribute__((ext_vector_type(4)));

__global__ __launch_bounds__(256) void center_loss_kernel(
    const float* __restrict__ x,
    const float* __restrict__ labels,
    const float* __restrict__ centers,
    float* __restrict__ partials)
{
    const int wave = threadIdx.x >> 6;
    const int lane = threadIdx.x & 63;
    const int row  = (blockIdx.x << 2) + wave;

    // ---- Issue label loads FIRST (the critical dependency) ----
    // 751 floats per row: 11 full strided rounds (704) + 47-lane tail.
    const float* __restrict__ lrow = labels + (size_t)row * NUM_CLASSES;
    float lv[12];
    #pragma unroll
    for (int k = 0; k < 11; ++k)
        lv[k] = __builtin_nontemporal_load(&lrow[lane + 64 * k]);
    lv[11] = (lane < NUM_CLASSES - 704)
                 ? __builtin_nontemporal_load(&lrow[704 + lane]) : 0.0f;

    // ---- x row loads issued behind labels; values needed only at the end ----
    const fvec4* __restrict__ xrow = (const fvec4*)(x + (size_t)row * FEAT_DIM);
    fvec4 xv[8];
    #pragma unroll
    for (int k = 0; k < 8; ++k)
        xv[k] = __builtin_nontemporal_load(&xrow[lane + 64 * k]);

    // ---- One-hot index: per-lane max, then 6-step wave shuffle-max ----
    int myidx = -1;
    #pragma unroll
    for (int k = 0; k < 12; ++k)
        if (lv[k] > 0.5f) myidx = lane + 64 * k;
    #pragma unroll
    for (int off = 32; off > 0; off >>= 1) {
        int other = __shfl_xor(myidx, off, 64);
        myidx = myidx > other ? myidx : other;
    }

    // ---- Gather center row (L2/L3-resident, reused ~11x), accumulate ----
    const fvec4* __restrict__ crow = (const fvec4*)(centers + (size_t)myidx * FEAT_DIM);
    float sum = 0.0f;
    #pragma unroll
    for (int k = 0; k < 8; ++k) {
        fvec4 cv = crow[lane + 64 * k];   // normal load: keep centers cached
        float dx = xv[k].x - cv.x;
        float dy = xv[k].y - cv.y;
        float dz = xv[k].z - cv.z;
        float dw = xv[k].w - cv.w;
        sum += dx * dx + dy * dy + dz * dz + dw * dw;
    }

    // ---- wave-64 reduction; lane 0 clips and stores ----
    #pragma unroll
    for (int off = 32; off > 0; off >>= 1)
        sum += __shfl_xor(sum, off, 64);

    if (lane == 0) {
        float ps = fminf(fmaxf(sum, 1e-12f), 1e12f);
        partials[row] = ps;        // deterministic store, no atomic
    }
}

// Reduce 8192 partials (32 KB, L2-hot) -> mean. One block, 256 threads.
__global__ __launch_bounds__(256) void reduce_kernel(
    const float* __restrict__ partials,
    float* __restrict__ out)
{
    const int tid = threadIdx.x;
    const fvec4* __restrict__ p4 = (const fvec4*)partials;  // 2048 vec4s

    float sum = 0.0f;
    #pragma unroll
    for (int k = 0; k < 8; ++k) {
        fvec4 v = p4[tid + 256 * k];
        sum += v.x + v.y + v.z + v.w;
    }

    #pragma unroll
    for (int off = 32; off > 0; off >>= 1)
        sum += __shfl_xor(sum, off, 64);

    __shared__ float s_part[4];
    const int wave = tid >> 6;
    const int lane = tid & 63;
    if (lane == 0) s_part[wave] = sum;
    __syncthreads();

    if (tid == 0) {
        float total = s_part[0] + s_part[1] + s_part[2] + s_part[3];
        out[0] = total * (1.0f / (float)BATCH);
    }
}

extern "C" void kernel_launch(void* const* d_in, const int* in_sizes, int n_in,
                              void* d_out, int out_size, void* d_ws, size_t ws_size,
                              hipStream_t stream)
{
    const float* x       = (const float*)d_in[0];
    const float* labels  = (const float*)d_in[1];
    const float* centers = (const float*)d_in[2];
    float* out      = (float*)d_out;
    float* partials = (float*)d_ws;   // 8192 floats, every slot overwritten

    center_loss_kernel<<<BATCH / 4, 256, 0, stream>>>(x, labels, centers, partials);
    reduce_kernel<<<1, 256, 0, stream>>>(partials, out);
}

// Round 5
// 115.338 us; speedup vs baseline: 1.0600x; 1.0600x over previous
//
#include <hip/hip_runtime.h>

// CenterLoss: mean over B rows of clip(||x_b - centers[label_b]||^2, 1e-12, 1e12)
// labels are exact one-hot fp32 rows -> dense dot == row gather (bit-exact).
//
// R1: 8192 same-address atomics serialized at the TCC (110 us kernel).
// R2: per-block partial stores + 1-block reduce -> 115.9 us total. Counter
//     evidence: top-5 dispatches are the harness's own 268 MB d_ws re-poison
//     (41 us @ 81% HBM peak); fixed reset ~95 us, our kernels ~20 us, of
//     which ~15 us is the mandatory 70 MB fetch at ~6.3 TB/s. Structural floor.
// R4: wave-per-row + nontemporal loads REGRESSED (122.3 us) — long VGPR
//     live-ranges + 6x ds_swizzle index-find beat by R2's LDS broadcast.
// R5: revert to R2 (measured best, at the computed floor).

#define BATCH 8192
#define NUM_CLASSES 751
#define FEAT_DIM 2048

__global__ __launch_bounds__(256) void center_loss_kernel(
    const float* __restrict__ x,
    const float* __restrict__ labels,
    const float* __restrict__ centers,
    float* __restrict__ partials)
{
    const int row = blockIdx.x;
    const int tid = threadIdx.x;

    // ---- Prefetch x row (independent of labels) to overlap HBM latency ----
    const float4* __restrict__ xrow = (const float4*)(x + (size_t)row * FEAT_DIM);
    float4 xv0 = xrow[tid];
    float4 xv1 = xrow[tid + 256];

    // ---- Find the one-hot index (coalesced scan of 751 floats) ----
    __shared__ int s_idx;
    const float* lrow = labels + (size_t)row * NUM_CLASSES;
    #pragma unroll
    for (int c = tid; c < NUM_CLASSES; c += 256) {
        if (lrow[c] > 0.5f) s_idx = c;   // exactly one thread writes
    }
    __syncthreads();
    const int idx = s_idx;

    // ---- Gather center row and accumulate squared distance ----
    const float4* __restrict__ crow = (const float4*)(centers + (size_t)idx * FEAT_DIM);
    float4 cv0 = crow[tid];
    float4 cv1 = crow[tid + 256];

    float dx = xv0.x - cv0.x, dy = xv0.y - cv0.y, dz = xv0.z - cv0.z, dw = xv0.w - cv0.w;
    float sum = dx * dx + dy * dy + dz * dz + dw * dw;
    dx = xv1.x - cv1.x; dy = xv1.y - cv1.y; dz = xv1.z - cv1.z; dw = xv1.w - cv1.w;
    sum += dx * dx + dy * dy + dz * dz + dw * dw;

    // ---- wave-64 shuffle reduction ----
    #pragma unroll
    for (int off = 32; off > 0; off >>= 1)
        sum += __shfl_down(sum, off, 64);

    __shared__ float s_part[4];
    const int wave = tid >> 6;
    const int lane = tid & 63;
    if (lane == 0) s_part[wave] = sum;
    __syncthreads();

    if (tid == 0) {
        float ps = s_part[0] + s_part[1] + s_part[2] + s_part[3];
        ps = fminf(fmaxf(ps, 1e-12f), 1e12f);   // clip
        partials[row] = ps;                      // deterministic store, no atomic
    }
}

// Reduce 8192 partials (32 KB, L2-hot) -> mean. One block, 256 threads.
__global__ __launch_bounds__(256) void reduce_kernel(
    const float* __restrict__ partials,
    float* __restrict__ out)
{
    const int tid = threadIdx.x;
    const float4* __restrict__ p4 = (const float4*)partials;  // 2048 float4s

    float sum = 0.0f;
    #pragma unroll
    for (int k = 0; k < 8; ++k) {
        float4 v = p4[tid + 256 * k];
        sum += v.x + v.y + v.z + v.w;
    }

    #pragma unroll
    for (int off = 32; off > 0; off >>= 1)
        sum += __shfl_down(sum, off, 64);

    __shared__ float s_part[4];
    const int wave = tid >> 6;
    const int lane = tid & 63;
    if (lane == 0) s_part[wave] = sum;
    __syncthreads();

    if (tid == 0) {
        float total = s_part[0] + s_part[1] + s_part[2] + s_part[3];
        out[0] = total * (1.0f / (float)BATCH);
    }
}

extern "C" void kernel_launch(void* const* d_in, const int* in_sizes, int n_in,
                              void* d_out, int out_size, void* d_ws, size_t ws_size,
                              hipStream_t stream)
{
    const float* x       = (const float*)d_in[0];
    const float* labels  = (const float*)d_in[1];
    const float* centers = (const float*)d_in[2];
    float* out      = (float*)d_out;
    float* partials = (float*)d_ws;   // 8192 floats, every slot overwritten

    center_loss_kernel<<<BATCH, 256, 0, stream>>>(x, labels, centers, partials);
    reduce_kernel<<<1, 256, 0, stream>>>(partials, out);
}